// Round 3
// baseline (347.588 us; speedup 1.0000x reference)
//
#include <hip/hip_runtime.h>
#include <hip/hip_bf16.h>

#define NLAT_IN  480
#define NLON_IN  960
#define NLAT_OUT 721
#define NLON_OUT 1440
#define KSIZE    9
#define NNZ      20
#define CH       32   // C_IN == C_OUT == 32

typedef __bf16 bf16x8 __attribute__((ext_vector_type(8)));
typedef float  f32x4  __attribute__((ext_vector_type(4)));
typedef unsigned u32x4 __attribute__((ext_vector_type(4)));

__device__ __forceinline__ unsigned short f2bf(float f) {
    unsigned u = __float_as_uint(f);
    u += 0x7fffu + ((u >> 16) & 1u);   // round-to-nearest-even
    return (unsigned short)(u >> 16);
}

// ---------------------------------------------------------------------------
// Kernel 1 (fused): blocks [0, NBLK_WEFF) compute weff, blocks
// [NBLK_WEFF, NBLK_WEFF+5768) do the bilinear resample. Independent passes.
// ---------------------------------------------------------------------------
#define W_TILE   180
#define IN_LD4   31            // 31 float4 = 124 input cols staged
#define LDS_PITCH 129
#define NBLK_WEFF 902          // ceil(721*20 / 16)
#define NBLK_RES  (8 * NLAT_OUT)

__global__ __launch_bounds__(256) void pre_kernel(
        const float* __restrict__ x,
        const float* __restrict__ weight,
        const float* __restrict__ psi_vals,
        unsigned short* __restrict__ xr,
        unsigned short* __restrict__ weff) {
    __shared__ float smem[KSIZE * CH * CH];   // 9216 floats = 36,864 B (union)

    const int bid = blockIdx.x;
    const int t   = threadIdx.x;

    if (bid < NBLK_WEFF) {
        // ---- weff[h][nz][oc][c] = sum_k weight[oc][c][k] * psi_vals[k][h][nz]
        float* wl = smem;                    // [k][oc][c]
        for (int i = 0; i < 9; ++i) {
            int lin = i * 256 + t;           // [0, 2304)
            if (lin < KSIZE * CH * CH / 4) {
                f32x4 v = *(const f32x4*)(weight + lin * 4);
                float vv[4] = {v.x, v.y, v.z, v.w};
#pragma unroll
                for (int q = 0; q < 4; ++q) {
                    int l4 = lin * 4 + q;    // = (oc*CH + c)*KSIZE + k
                    int k  = l4 % KSIZE;
                    int occ = l4 / KSIZE;    // oc*CH + c
                    wl[k * (CH * CH) + occ] = vv[q];
                }
            }
        }
        __syncthreads();

        int hnz = bid * 16 + (t >> 4);
        int cp  = t & 15;
        if (hnz >= NLAT_OUT * NNZ) return;

        float p[KSIZE];
#pragma unroll
        for (int k = 0; k < KSIZE; ++k)
            p[k] = psi_vals[(size_t)k * (NLAT_OUT * NNZ) + hnz];

        unsigned* outp = (unsigned*)weff + (size_t)hnz * (CH * CH / 2) + cp;
#pragma unroll 4
        for (int oc = 0; oc < CH; ++oc) {
            float a0 = 0.f, a1 = 0.f;
            const float* wb = wl + oc * CH + cp * 2;
#pragma unroll
            for (int k = 0; k < KSIZE; ++k) {
                a0 += wb[k * (CH * CH)]     * p[k];
                a1 += wb[k * (CH * CH) + 1] * p[k];
            }
            outp[oc * 16] = (unsigned)f2bf(a0) | ((unsigned)f2bf(a1) << 16);
        }
        return;
    }

    // ---- resample: (480,960) -> (721,1440), channel-last bf16 out ----
    float* ld = smem;                        // uses 2*CH*LDS_PITCH = 8256 floats
    int bid2 = bid - NBLK_WEFF;
    int bx = bid2 & 7;
    int h  = bid2 >> 3;
    int wb = bx * W_TILE;
    int base_in = bx * (W_TILE * 2 / 3);     // = bx*120

    float pos_h = (float)h * (479.0f / 720.0f);
    int h0 = (int)floorf(pos_h);
    if (h0 < 0) h0 = 0;
    if (h0 > NLAT_IN - 2) h0 = NLAT_IN - 2;
    float fh = pos_h - (float)h0;

    for (int i = 0; i < 8; ++i) {
        int lin = i * 256 + t;               // [0, 1984)
        if (lin < 2 * CH * IN_LD4) {
            int r   = lin / (CH * IN_LD4);
            int rem = lin - r * (CH * IN_LD4);
            int c   = rem / IN_LD4;
            int j   = rem - c * IN_LD4;
            int src = base_in + 4 * j;
            if (src >= NLON_IN) src -= NLON_IN;      // only last block
            f32x4 v = *(const f32x4*)(x + ((size_t)c * NLAT_IN + h0 + r) * NLON_IN + src);
            float* dst = ld + (r * CH + c) * LDS_PITCH + 4 * j;
            dst[0] = v.x; dst[1] = v.y; dst[2] = v.z; dst[3] = v.w;
        }
    }
    __syncthreads();

    float ifh = 1.0f - fh;
    for (int i = 0; i < 3; ++i) {
        int d = i * 256 + t;                 // [0, 768)
        if (d >= W_TILE * (CH / 8)) break;   // 720 items
        int w_l = d >> 2;
        int cg  = d & 3;                     // channel group of 8
        int w = wb + w_l;
        float pos_w = (float)w * ((float)NLON_IN / (float)NLON_OUT);
        int w0 = (int)floorf(pos_w);
        float fw = pos_w - (float)w0;
        int wl0 = w0 - base_in;              // [0, 120]
        float ifw = 1.0f - fw;

        unsigned rr[4];
#pragma unroll
        for (int j = 0; j < 4; ++j) {
            int c = cg * 8 + j * 2;
            const float* r0 = ld + c * LDS_PITCH + wl0;
            const float* r1 = r0 + CH * LDS_PITCH;
            float v0 = ifh * (ifw * r0[0] + fw * r0[1]) + fh * (ifw * r1[0] + fw * r1[1]);
            const float* q0 = r0 + LDS_PITCH;
            const float* q1 = r1 + LDS_PITCH;
            float v1 = ifh * (ifw * q0[0] + fw * q0[1]) + fh * (ifw * q1[0] + fw * q1[1]);
            rr[j] = (unsigned)f2bf(v0) | ((unsigned)f2bf(v1) << 16);
        }
        u32x4 uv; uv[0] = rr[0]; uv[1] = rr[1]; uv[2] = rr[2]; uv[3] = rr[3];
        *(u32x4*)((unsigned*)xr + ((size_t)h * NLON_OUT + w) * (CH / 2) + cg * 4) = uv;
    }
}

// ---------------------------------------------------------------------------
// Kernel 2: disco conv via MFMA — 2-phase double-buffered h-walking blocks.
// Block = 512 thr (8 waves), tile = 4 h-rows x 96 w-cols.
//   wave = (jh<<1)|wq : jh = h-row (0..3), wq = 48-col half. The wq-pair of
//   waves reads the SAME weff[h][nz] fragments -> second read hits L1, so
//   weff L2 traffic is back to the WC=96 level (~434 MB, half of round 2).
// Each block walks CHUNK_H=3 consecutive h-tiles at fixed 96-col strip with
// double-buffered LDS (2 x 64 KiB): per iteration, STAGE(t+1 -> buf^1) is
// issued BEFORE compute(t from buf), so the barrier's vmcnt(0) drain finds
// the loads already landed (T3 "minimum 2-phase" pipeline). One barrier per
// tile; staging latency hides under ~4K cyc of MFMA+LDS work.
// LDS XOR-swizzle (T2, both-sides, chunk-local): global source pre-swizzled
//   (q ^= (col>>1)&3 within each 16-col chunk), same XOR on the read ->
//   conflict-free (round 2 measured: SQ_LDS_BANK_CONFLICT = 0).
// A-fragments (weff) software-pipelined depth-4 (static slot indices).
// Fragment maps (HW-verified): A[m=lane&15][k=quad*8+j],
// B[k=quad*8+j][n=lane&15], D[row=quad*4+r][col=lane&15].
// ---------------------------------------------------------------------------
#define ST_ROWS 8
#define ST_COLS 128
#define TILE_E  (ST_ROWS * ST_COLS * CH)    // 32768 shorts = 64 KiB
#define CHUNK_H 3                           // h-tiles walked per block
#define NHBLK   181                         // ceil(721/4)
#define NCHUNK  ((NHBLK + CHUNK_H - 1) / CHUNK_H)   // 61
#define NWBLK   15                          // 1440 / 96
#define NBLK_D  (NCHUNK * NWBLK)            // 915

__global__ __launch_bounds__(512, 2) void disco_kernel(
        const unsigned short* __restrict__ xr,     // [721][1440][32] bf16
        const unsigned short* __restrict__ weff,   // [721][20][32][32] bf16
        const int* __restrict__ psi_hi,            // [721][20]
        const int* __restrict__ psi_dw,            // [721][20]
        float* __restrict__ out) {                 // [32][721][1440]
    __shared__ unsigned short st[2 * TILE_E];      // 128 KiB

    const int bid   = blockIdx.x;
    const int wblk  = bid % NWBLK;
    const int chunk = bid / NWBLK;
    const int hb0   = chunk * CHUNK_H;
    const int nt    = (NHBLK - hb0) < CHUNK_H ? (NHBLK - hb0) : CHUNK_H;
    const int wbase_blk = wblk * 96;

    const int wave = threadIdx.x >> 6;
    const int lane = threadIdx.x & 63;
    const int l15  = lane & 15;
    const int quad = lane >> 4;
    const int c0   = quad * 8;
    const int jh   = wave >> 1;          // h-row within tile (0..3)
    const int wq   = wave & 1;           // 48-col half

    // Per-lane swizzled source offset within a 16-col (1024 B) chunk:
    // lane covers col = lane>>2, sub-block q = lane&3; fetch logical
    // (col, q ^ ((col>>1)&3)) so the linear LDS write lands it swizzled.
    const int swz = ((lane >> 2) << 5) + (((lane & 3) ^ ((lane >> 3) & 3)) << 3);

    int cstart = wbase_blk - 16;
    if (cstart < 0) cstart += NLON_OUT;  // multiple of 16

    // ---- prologue: stage tile 0 into buf 0 ----
    {
        const int h0 = hb0 * 4;
        for (int i = wave; i < ST_ROWS * (ST_COLS / 16); i += 8) {
            int r = i >> 3, ck = i & 7;
            int gh = h0 - 2 + r;
            gh = gh < 0 ? 0 : (gh > NLAT_OUT - 1 ? NLAT_OUT - 1 : gh);
            int gc = cstart + ck * 16;
            if (gc >= NLON_OUT) gc -= NLON_OUT;   // chunk never crosses wrap
            const unsigned short* gp = xr + ((size_t)gh * NLON_OUT + gc) * CH + swz;
            unsigned short* lp = st + (r * ST_COLS + ck * 16) * CH;
            __builtin_amdgcn_global_load_lds(
                (const __attribute__((address_space(1))) void*)gp,
                (__attribute__((address_space(3))) void*)lp, 16, 0, 0);
        }
    }
    __syncthreads();

    for (int t = 0; t < nt; ++t) {
        // ---- issue next tile's stage EARLY (into buf^1) ----
        if (t + 1 < nt) {
            const int h0n = (hb0 + t + 1) * 4;
            unsigned short* bufn = st + ((t + 1) & 1) * TILE_E;
            for (int i = wave; i < ST_ROWS * (ST_COLS / 16); i += 8) {
                int r = i >> 3, ck = i & 7;
                int gh = h0n - 2 + r;
                gh = gh < 0 ? 0 : (gh > NLAT_OUT - 1 ? NLAT_OUT - 1 : gh);
                int gc = cstart + ck * 16;
                if (gc >= NLON_OUT) gc -= NLON_OUT;
                const unsigned short* gp = xr + ((size_t)gh * NLON_OUT + gc) * CH + swz;
                unsigned short* lp = bufn + (r * ST_COLS + ck * 16) * CH;
                __builtin_amdgcn_global_load_lds(
                    (const __attribute__((address_space(1))) void*)gp,
                    (__attribute__((address_space(3))) void*)lp, 16, 0, 0);
            }
        }

        const int h0 = (hb0 + t) * 4;
        const int h  = h0 + jh;
        const unsigned short* bt = st + (t & 1) * TILE_E;

        if (h < NLAT_OUT) {
            const unsigned short* weff_h = weff + (size_t)h * (NNZ * CH * CH);
            const int* hip_ = psi_hi + h * NNZ;
            const int* dwp  = psi_dw + h * NNZ;

            // ---- A prologue: prefetch nz=0..3 weff fragments + psi ----
            bf16x8 pa0[4], pa1[4];
            int phi[4], pdw[4];
#pragma unroll
            for (int q = 0; q < 4; ++q) {
                const unsigned short* wp = weff_h + q * (CH * CH);
                pa0[q] = *(const bf16x8*)(wp + l15 * CH + c0);
                pa1[q] = *(const bf16x8*)(wp + (16 + l15) * CH + c0);
                phi[q] = hip_[q];
                pdw[q] = dwp[q];
            }

            f32x4 acc[2][3] = {};
            const int wcol0 = 16 + wq * 48 + l15;    // LDS col, s=0

#pragma unroll
            for (int nz = 0; nz < NNZ; ++nz) {
                const int sl = nz & 3;               // static after unroll
                bf16x8 a0 = pa0[sl];
                bf16x8 a1 = pa1[sl];
                int hi = phi[sl];
                int dw = pdw[sl];
                if (nz + 4 < NNZ) {                  // refill 4 nz ahead
                    const unsigned short* wp = weff_h + (nz + 4) * (CH * CH);
                    pa0[sl] = *(const bf16x8*)(wp + l15 * CH + c0);
                    pa1[sl] = *(const bf16x8*)(wp + (16 + l15) * CH + c0);
                    phi[sl] = hip_[nz + 4];
                    pdw[sl] = dwp[nz + 4];
                }
                int shift = dw > 720 ? dw - NLON_OUT : dw;   // range [-10,10]
                int rloc  = hi - h0 + 2;                     // [0, 7]
                int cbase = wcol0 + shift;                   // [6, 89]
                // read-side XOR select: ((col>>1)&3) invariant under +s*16
                int sel   = ((((cbase >> 1) & 3) ^ quad) << 3);
                const unsigned short* bp =
                    bt + (size_t)rloc * (ST_COLS * CH) + cbase * CH + sel;
#pragma unroll
                for (int s = 0; s < 3; ++s) {
                    bf16x8 b = *(const bf16x8*)(bp + s * 16 * CH);
                    acc[0][s] = __builtin_amdgcn_mfma_f32_16x16x32_bf16(a0, b, acc[0][s], 0, 0, 0);
                    acc[1][s] = __builtin_amdgcn_mfma_f32_16x16x32_bf16(a1, b, acc[1][s], 0, 0, 0);
                }
            }

#pragma unroll
            for (int hh = 0; hh < 2; ++hh)
#pragma unroll
                for (int s = 0; s < 3; ++s)
#pragma unroll
                    for (int r = 0; r < 4; ++r) {
                        int oc = hh * 16 + quad * 4 + r;
                        int w  = wbase_blk + wq * 48 + s * 16 + l15;
                        out[((size_t)oc * NLAT_OUT + h) * NLON_OUT + w] = acc[hh][s][r];
                    }
        }
        __syncthreads();
    }
}

// ---------------------------------------------------------------------------
extern "C" void kernel_launch(void* const* d_in, const int* in_sizes, int n_in,
                              void* d_out, int out_size, void* d_ws, size_t ws_size,
                              hipStream_t stream) {
    const float* x        = (const float*)d_in[0];
    const float* weight   = (const float*)d_in[1];
    const float* psi_vals = (const float*)d_in[2];
    const int*   psi_hi   = (const int*)d_in[3];
    const int*   psi_dw   = (const int*)d_in[4];
    float* out = (float*)d_out;

    // workspace: xr bf16 [721][1440][32] = 66,447,360 B, then
    // weff bf16 [721][20][32][32] = 29,532,160 B
    unsigned short* xr = (unsigned short*)d_ws;
    unsigned short* wf = (unsigned short*)((char*)d_ws + (size_t)NLAT_OUT * NLON_OUT * CH * 2);

    {
        pre_kernel<<<NBLK_WEFF + NBLK_RES, 256, 0, stream>>>(x, weight, psi_vals, xr, wf);
    }
    {
        disco_kernel<<<NBLK_D, 512, 0, stream>>>(xr, wf, psi_hi, psi_dw, out);
    }
}